// Round 14
// baseline (1827.454 us; speedup 1.0000x reference)
//
#include <hip/hip_runtime.h>
#include <cstdint>
#include <cstddef>

// ---------------- constants ----------------
#define H160   160
#define HD     86          // h-74
#define GW     72          // grid width (72x72 points)
#define PG     5184        // 72*72
#define P66    4356        // 66*66
#define NPAIR  2178        // P66/2
#define IDX146 21316       // 146*146
#define NVNH   5625        // 75*75
#define SELF_CAND 19687    // 3*5625 + 37*75 + 37
#define CHUNK  2625        // candidates per chunk (39375 = 15*2625)
#define NCHUNK 15
#define NSLOT  21
#define SLOTLEN 125
typedef unsigned long long u64;
struct F3 { float x, y, z; };

// ---------------- k0: transpose seq -> seqT3[t][x][y][c] (3-ch interleaved) ----
__global__ void k0_transpose(const float* __restrict__ seq, float* __restrict__ seqT3) {
  int t7 = blockIdx.y;           // frame 0..6
  int x  = blockIdx.x;           // col 0..159
  int y  = threadIdx.x;          // row 0..159
  int o = ((t7 * H160 + x) * H160 + y) * 3;
  seqT3[o + 0] = seq[(0 * 7 + t7) * 25600 + y * H160 + x];
  seqT3[o + 1] = seq[(1 * 7 + t7) * 25600 + y * H160 + x];
  seqT3[o + 2] = seq[(2 * 7 + t7) * 25600 + y * H160 + x];
}

// ---------------- init state keys to max ----------------
__global__ void k_init(u64* __restrict__ sk, int n) {
  int i = (int)blockIdx.x * 256 + threadIdx.x;
  if (i < n) sk[i] = ~0ULL;
}

// ---------------- k1: per-candidate boxed distance field (R10 verbatim —
// bitwise-replicates numpy sequential fp32 cumsum box15; Markstein div-by-3;
// phase-1 emits row-boxed values via static 16-ring; 25.1 KB LDS). ----
__global__ __launch_bounds__(128) void k1_dist(const float* __restrict__ seqT3,
                                               float* __restrict__ wsD, int chunkBase) {
  __shared__ float vb[HD][73];   // row-boxed values, padded stride 73
  const float R3 = 0.33333334f;  // RN(1/3)
  int cand = chunkBase + (int)blockIdx.x;
  int ts = cand / NVNH;
  int rr = cand % NVNH;
  int vs = rr / 75;
  int hv = rr % 75;
  int t = threadIdx.x;
  if (t < HD) {
    const F3* pa = (const F3*)seqT3 + ((ts * H160 + hv) * H160 + (vs + t));
    const F3* pb = (const F3*)seqT3 + ((3  * H160 + 37) * H160 + (37 + t));
    float c0 = 0.f;
    float ring[16];
#pragma unroll 1
    for (int blk = 0; blk < 5; ++blk) {          // u = 0..79 in 16-step frames
      int x0 = blk * 16;
#pragma unroll
      for (int half = 0; half < 2; ++half) {     // 8-load / 8-compute halves
        F3 Av[8], Bv[8];
#pragma unroll
        for (int k = 0; k < 8; ++k) {
          int u = x0 + half * 8 + k;
          Av[k] = pa[u * H160];
          Bv[k] = pb[u * H160];
        }
#pragma unroll
        for (int k = 0; k < 8; ++k) {
          int u  = x0 + half * 8 + k;
          int ki = half * 8 + k;                 // = u & 15 (static)
          float d0 = __fsub_rn(Av[k].x, Bv[k].x);
          float d1 = __fsub_rn(Av[k].y, Bv[k].y);
          float d2 = __fsub_rn(Av[k].z, Bv[k].z);
          float s  = __fadd_rn(__fadd_rn(__fmul_rn(d0, d0), __fmul_rn(d1, d1)), __fmul_rn(d2, d2));
          float q0 = __fmul_rn(s, R3);
          float e  = __builtin_fmaf(-3.0f, q0, s);
          float dd = __builtin_fmaf(e, R3, q0);
          c0 = __fadd_rn(c0, dd);
          ring[ki] = c0;
          if (u >= 14) {
            int j = u - 14;
            vb[t][j] = (j == 0) ? c0 : __fsub_rn(c0, ring[(ki + 1) & 15]); // c_{u-15}
          }
        }
      }
    }
    {                                            // tail u = 80..85 (ki = k, static)
      F3 Av[6], Bv[6];
#pragma unroll
      for (int k = 0; k < 6; ++k) {
        Av[k] = pa[(80 + k) * H160];
        Bv[k] = pb[(80 + k) * H160];
      }
#pragma unroll
      for (int k = 0; k < 6; ++k) {
        float d0 = __fsub_rn(Av[k].x, Bv[k].x);
        float d1 = __fsub_rn(Av[k].y, Bv[k].y);
        float d2 = __fsub_rn(Av[k].z, Bv[k].z);
        float s  = __fadd_rn(__fadd_rn(__fmul_rn(d0, d0), __fmul_rn(d1, d1)), __fmul_rn(d2, d2));
        float q0 = __fmul_rn(s, R3);
        float e  = __builtin_fmaf(-3.0f, q0, s);
        float dd = __builtin_fmaf(e, R3, q0);
        c0 = __fadd_rn(c0, dd);
        ring[k] = c0;                            // (80+k)&15 = k
        vb[t][66 + k] = __fsub_rn(c0, ring[(k + 1) & 15]); // c_{65+k}
      }
    }
  }
  __syncthreads();
  if (t < GW) {
    float cc = 0.f;
    float ring[16];
    float* D = wsD + (size_t)blockIdx.x * PG;
#pragma unroll
    for (int r = 0; r < HD; ++r) {
      float val = vb[r][t];
      cc = __fadd_rn(cc, val);
      ring[r & 15] = cc;
      if (r >= 14) {
        int gy = r - 14;
        float out = (gy == 0) ? cc : __fsub_rn(cc, ring[(r - 15) & 15]);
        D[gy * GW + t] = out;
      }
    }
  }
}

// ---------------- k2: banked top-14 via u64 sort keys (R4/R10 version — no
// state-threshold filter; that filter caused call-to-call divergence). ----
__global__ __launch_bounds__(256) void k2_topk(const float* __restrict__ wsD,
                                               u64* __restrict__ sk, int chunkBase) {
  __shared__ u64 lk[5][14][64];
  int tid = threadIdx.x;
  int w = tid >> 6, lane = tid & 63;
  int s = blockIdx.y;
  int pid = (int)blockIdx.x * 64 + lane;
  int st  = (w == 0) ? 96 : (w - 1) * 32;
  int cnt = (w == 0) ? 29 : 32;

  if (w == 0) {
#pragma unroll
    for (int k = 0; k < 14; ++k)
      lk[4][k][lane] = sk[(size_t)(s * 14 + k) * PG + pid];
  }
  float dv[32];
  const float* Dp = wsD + (size_t)(s * SLOTLEN + st) * PG + pid;
#pragma unroll
  for (int u = 0; u < 32; ++u)
    if (u < cnt) dv[u] = Dp[(size_t)u * PG];

  u64 key[14];
#pragma unroll
  for (int k = 0; k < 14; ++k) key[k] = ~0ULL;
  int cand0 = chunkBase + s * SLOTLEN + st;
#pragma unroll
  for (int u = 0; u < 32; ++u) {
    if (u < cnt) {
      int cand = cand0 + u;
      if (cand != SELF_CAND) {
        u64 nk = ((u64)__float_as_uint(dv[u]) << 32) | (unsigned)cand;
        if (nk < key[13]) {
#pragma unroll
          for (int j = 13; j >= 1; --j)
            key[j] = (nk < key[j - 1]) ? key[j - 1] : ((nk < key[j]) ? nk : key[j]);
          if (nk < key[0]) key[0] = nk;
        }
      }
    }
  }
#pragma unroll
  for (int k = 0; k < 14; ++k) lk[w][k][lane] = key[k];
  __syncthreads();
  if (w != 0) return;

  int h0 = 0, h1 = 0, h2 = 0, h3 = 0, h4 = 0;
  u64 a0 = lk[0][0][lane], a1 = lk[1][0][lane], a2 = lk[2][0][lane],
      a3 = lk[3][0][lane], a4 = lk[4][0][lane];
#pragma unroll
  for (int o = 0; o < 14; ++o) {
    u64 b01 = a0 < a1 ? a0 : a1; int j01 = a0 < a1 ? 0 : 1;
    u64 b23 = a2 < a3 ? a2 : a3; int j23 = a2 < a3 ? 2 : 3;
    u64 b03 = b01 < b23 ? b01 : b23; int j03 = b01 < b23 ? j01 : j23;
    u64 best = b03 < a4 ? b03 : a4; int bj = b03 < a4 ? j03 : 4;
    sk[(size_t)(s * 14 + o) * PG + pid] = best;
    h0 += (bj == 0); h1 += (bj == 1); h2 += (bj == 2); h3 += (bj == 3); h4 += (bj == 4);
    int c0 = h0 < 14 ? h0 : 13, c1 = h1 < 14 ? h1 : 13, c2 = h2 < 14 ? h2 : 13,
        c3 = h3 < 14 ? h3 : 13, c4 = h4 < 14 ? h4 : 13;
    a0 = lk[0][c0][lane]; if (h0 >= 14) a0 = ~0ULL;
    a1 = lk[1][c1][lane]; if (h1 >= 14) a1 = ~0ULL;
    a2 = lk[2][c2][lane]; if (h2 >= 14) a2 = ~0ULL;
    a3 = lk[3][c3][lane]; if (h3 >= 14) a3 = ~0ULL;
    a4 = lk[4][c4][lane]; if (h4 >= 14) a4 = ~0ULL;
  }
}

// ---------------- merge 21 slot lists -> final 14 indices ----------------
__global__ __launch_bounds__(64) void k_merge(const u64* __restrict__ sk,
                                              int* __restrict__ fsi) {
  int pid = (int)blockIdx.x * 64 + threadIdx.x;
  int gy = pid / GW, gx = pid % GW;
  int cur[NSLOT];
#pragma unroll
  for (int s = 0; s < NSLOT; ++s) cur[s] = 0;
  for (int o = 0; o < 14; ++o) {
    u64 bk = ~0ULL; int bs = 0;
#pragma unroll
    for (int s = 0; s < NSLOT; ++s) {
      int cc = cur[s] < 14 ? cur[s] : 13;
      u64 kk = sk[(size_t)(s * 14 + cc) * PG + pid];
      if (cur[s] >= 14) kk = ~0ULL;
      if (kk < bk) { bk = kk; bs = s; }
    }
#pragma unroll
    for (int s = 0; s < NSLOT; ++s) cur[s] += (bs == s) ? 1 : 0;
    int cand = (int)(unsigned)(bk & 0xffffffffULL);
    int ts = cand / NVNH;
    int rr = cand % NVNH;
    int vs = rr / 75, hv = rr % 75;
    fsi[o * PG + pid] = ts * IDX146 + (gy + vs) * 146 + (gx + hv);
  }
}

// ---------------- k3: build x_f = [layers(147), wts(3)] per neighbor slot ----------
__global__ void k3_layers(const float* __restrict__ seq, const int* __restrict__ fsi,
                          float* __restrict__ X) {
  int n = blockIdx.y;                       // 0..14
  int p = (int)blockIdx.x * 256 + threadIdx.x;
  if (p >= P66) return;
  int yo = p / 66, xo = p % 66;
  int y = yo + 6, x = xo + 6;
  float sv0 = seq[(0 * 7 + 3) * 25600 + (41 + y) * H160 + (41 + x)];
  float sv1 = seq[(1 * 7 + 3) * 25600 + (41 + y) * H160 + (41 + x)];
  float sv2 = seq[(2 * 7 + 3) * 25600 + (41 + y) * H160 + (41 + x)];
  float w0 = 0.f, w1 = 0.f, w2 = 0.f;
  for (int mv = 0; mv < 7; ++mv) {
    int dy = (y - mv) % 7; int gyy = y - dy;
    for (int mh = 0; mh < 7; ++mh) {
      int dx = (x - mh) % 7; int gxx = x - dx;
      int q = mv * 7 + mh;
      float v0, v1, v2;
      if (n == 0) { v0 = sv0; v1 = sv1; v2 = sv2; }
      else {
        int idx = fsi[(n - 1) * PG + gyy * GW + gxx];
        int fi = idx / IDX146; int rem = idx % IDX146;
        int pv = rem / 146, ph = rem % 146;
        int base = (4 + pv + dy) * H160 + (4 + ph + dx);
        v0 = seq[(0 * 7 + fi) * 25600 + base];
        v1 = seq[(1 * 7 + fi) * 25600 + base];
        v2 = seq[(2 * 7 + fi) * 25600 + base];
      }
      X[(size_t)(n * 150 + q * 3 + 0) * P66 + p] = v0;
      X[(size_t)(n * 150 + q * 3 + 1) * P66 + p] = v1;
      X[(size_t)(n * 150 + q * 3 + 2) * P66 + p] = v2;
      float e0 = v0 - sv0, e1 = v1 - sv1, e2 = v2 - sv2;
      w0 += e0 * e0; w1 += e1 * e1; w2 += e2 * e2;
    }
  }
  X[(size_t)(n * 150 + 147) * P66 + p] = w0 / 49.f;
  X[(size_t)(n * 150 + 148) * P66 + p] = w1 / 49.f;
  X[(size_t)(n * 150 + 149) * P66 + p] = w2 / 49.f;
}

// ---------------- k4a interior: px (3..62)x(3..62) need no reflection —
// 7 contiguous row loads from one base per ic, all with static immediate
// offsets (max 1608 B < 4096). FMA order (ic,ky,kx) -> bit-identical. ----
__global__ void k4a_in(const float* __restrict__ in, const float* __restrict__ w,
                       float* __restrict__ out) {
  int g = blockIdx.y;
  int q = (int)blockIdx.x * 256 + threadIdx.x;
  if (q >= 3600) return;
  int yi = q / 60, xi = q % 60;
  int p = (yi + 3) * 66 + (xi + 3);
  int o0 = g * 3;
  float a0 = 0.f, a1 = 0.f, a2 = 0.f;
#pragma unroll
  for (int ic = 0; ic < 3; ++ic) {
    const float* ip = in + (size_t)(o0 + ic) * P66 + yi * 66 + xi;  // window top-left
    const float* wp = w + (size_t)o0 * 147 + ic * 49;
#pragma unroll
    for (int ky = 0; ky < 7; ++ky) {
      const float* row = ip + ky * 66;
#pragma unroll
      for (int kx = 0; kx < 7; ++kx) {
        float v = row[kx];
        int wi = ky * 7 + kx;
        a0 = fmaf(v, wp[wi],       a0);
        a1 = fmaf(v, wp[147 + wi], a1);
        a2 = fmaf(v, wp[294 + wi], a2);
      }
    }
  }
  out[(size_t)(o0 + 0) * P66 + p] = a0;
  out[(size_t)(o0 + 1) * P66 + p] = a1;
  out[(size_t)(o0 + 2) * P66 + p] = a2;
}

// ---------------- k4a border: compacted 756-px border list, generic reflect
// path (R13 k4a verbatim inner loop). Compaction keeps waves dense. ----
__global__ void k4a_bd(const float* __restrict__ in, const float* __restrict__ w,
                       float* __restrict__ out) {
  int g = blockIdx.y;
  int q = (int)blockIdx.x * 256 + threadIdx.x;
  if (q >= 756) return;
  int yo, xo;
  if (q < 198)      { yo = q / 66;            xo = q % 66; }            // top 3 rows
  else if (q < 396) { int r = q - 198; yo = 63 + r / 66; xo = r % 66; } // bottom 3 rows
  else              { int r = q - 396; yo = 3 + r / 6; int c = r % 6;
                      xo = (c < 3) ? c : (c + 60); }                    // side cols
  int p = yo * 66 + xo;
  int o0 = g * 3;
  int iyt[7], ixt[7];
#pragma unroll
  for (int k = 0; k < 7; ++k) {
    int vy = yo + k - 3; iyt[k] = (vy < 0 ? -vy : (vy > 65 ? 130 - vy : vy)) * 66;
    int vx = xo + k - 3; ixt[k] = vx < 0 ? -vx : (vx > 65 ? 130 - vx : vx);
  }
  float a0 = 0.f, a1 = 0.f, a2 = 0.f;
#pragma unroll
  for (int ic = 0; ic < 3; ++ic) {
    const float* ip = in + (size_t)(o0 + ic) * P66;
    const float* wp = w + (size_t)o0 * 147 + ic * 49;
#pragma unroll
    for (int ky = 0; ky < 7; ++ky) {
      const float* row = ip + iyt[ky];
#pragma unroll
      for (int kx = 0; kx < 7; ++kx) {
        float v = row[ixt[kx]];
        int wi = ky * 7 + kx;
        a0 = fmaf(v, wp[wi],       a0);
        a1 = fmaf(v, wp[147 + wi], a1);
        a2 = fmaf(v, wp[294 + wi], a2);
      }
    }
  }
  out[(size_t)(o0 + 0) * P66 + p] = a0;
  out[(size_t)(o0 + 1) * P66 + p] = a1;
  out[(size_t)(o0 + 2) * P66 + p] = a2;
}

// ---------------- k4b: 1x1 conv, groups of 150, 10 outputs x 2 px (float2) ----
__global__ void k4b_f(const float* __restrict__ in, const float* __restrict__ w,
                      float* __restrict__ out) {
  int ob = blockIdx.y * 10;
  int q = (int)blockIdx.x * 256 + threadIdx.x;
  if (q >= NPAIR) return;
  int p = q * 2;
  int gb = (ob / 150) * 150;
  float2 acc[10];
#pragma unroll
  for (int j = 0; j < 10; ++j) { acc[j].x = 0.f; acc[j].y = 0.f; }
  const float* ip = in + (size_t)gb * P66 + p;
  const float* w0 = w + (size_t)ob * 150;
  for (int f = 0; f < 150; ++f) {
    float2 v = *(const float2*)&ip[(size_t)f * P66];    // P66 even, p even -> 8B aligned
#pragma unroll
    for (int j = 0; j < 10; ++j) {
      float wv = w0[j * 150 + f];
      acc[j].x = fmaf(v.x, wv, acc[j].x);
      acc[j].y = fmaf(v.y, wv, acc[j].y);
    }
  }
#pragma unroll
  for (int j = 0; j < 10; ++j)
    *(float2*)&out[(size_t)(ob + j) * P66 + p] = acc[j];
}

// ---------------- k4c: neighbor-mix 1x1, 2 px/thread (float2) ----------
template<int NI, int NO>
__global__ void k4c_n(const float* __restrict__ in, const float* __restrict__ w,
                      const float* __restrict__ bias, float* __restrict__ out, int withbias) {
  int f = blockIdx.y;                       // 0..149
  int q = (int)blockIdx.x * 256 + threadIdx.x;
  if (q >= NPAIR) return;
  int p = q * 2;
  float2 acc[NO];
#pragma unroll
  for (int j = 0; j < NO; ++j) { acc[j].x = 0.f; acc[j].y = 0.f; }
#pragma unroll
  for (int nn = 0; nn < NI; ++nn) {
    float2 v = *(const float2*)&in[(size_t)(nn * 150 + f) * P66 + p];
#pragma unroll
    for (int j = 0; j < NO; ++j) {
      float wv = w[(f * NO + j) * NI + nn];
      acc[j].x = fmaf(v.x, wv, acc[j].x);
      acc[j].y = fmaf(v.y, wv, acc[j].y);
    }
  }
#pragma unroll
  for (int j = 0; j < NO; ++j) {
    float2 r = acc[j];
    if (withbias) {
      float b = bias[j * 150 + f];
      r.x += b; r.x = r.x > 0.f ? r.x : 0.f;
      r.y += b; r.y = r.y > 0.f ? r.y : 0.f;
    }
    *(float2*)&out[(size_t)(j * 150 + f) * P66 + p] = r;
  }
}

// ---------------- BN (train-mode batch stats over 66x66) + relu, in place --------
__global__ void k_bn(float* __restrict__ x, const float* __restrict__ g,
                     const float* __restrict__ be) {
  int c = blockIdx.x;
  float* xp = x + (size_t)c * P66;
  __shared__ float red[256];
  int t = threadIdx.x;
  float s = 0.f;
  for (int p = t; p < P66; p += 256) s += xp[p];
  red[t] = s; __syncthreads();
  for (int off = 128; off > 0; off >>= 1) { if (t < off) red[t] += red[t + off]; __syncthreads(); }
  float m = red[0] / (float)P66;
  __syncthreads();
  float s2 = 0.f;
  for (int p = t; p < P66; p += 256) { float dd = xp[p] - m; s2 += dd * dd; }
  red[t] = s2; __syncthreads();
  for (int off = 128; off > 0; off >>= 1) { if (t < off) red[t] += red[t + off]; __syncthreads(); }
  float var = red[0] / (float)P66;
  float sc = g[c] / sqrtf(var + 1e-5f);
  float sh = be[c] - m * sc;
  for (int p = t; p < P66; p += 256) { float r = fmaf(xp[p], sc, sh); xp[p] = r > 0.f ? r : 0.f; }
}

// ---------------- final: w_f4 (150->3) + b4, out = valid - y ----------------------
__global__ void k_final(const float* __restrict__ in, const float* __restrict__ wf,
                        const float* __restrict__ b4, const float* __restrict__ seq,
                        float* __restrict__ out) {
  int p = (int)blockIdx.x * 256 + threadIdx.x;
  if (p >= P66) return;
  int yo = p / 66, xo = p % 66;
  float a0 = 0.f, a1 = 0.f, a2 = 0.f;
  for (int f = 0; f < 150; ++f) {
    float v = in[(size_t)f * P66 + p];
    a0 = fmaf(v, wf[f],       a0);
    a1 = fmaf(v, wf[150 + f], a1);
    a2 = fmaf(v, wf[300 + f], a2);
  }
  float y0 = a0 + b4[0], y1 = a1 + b4[1], y2 = a2 + b4[2];
  int vo = (47 + yo) * H160 + (47 + xo);
  out[0 * P66 + p] = seq[(0 * 7 + 3) * 25600 + vo] - y0;
  out[1 * P66 + p] = seq[(1 * 7 + 3) * 25600 + vo] - y1;
  out[2 * P66 + p] = seq[(2 * 7 + 3) * 25600 + vo] - y2;
}

extern "C" void kernel_launch(void* const* d_in, const int* in_sizes, int n_in,
                              void* d_out, int out_size, void* d_ws, size_t ws_size,
                              hipStream_t stream) {
  const float* seq   = (const float*)d_in[0];   // (1,3,7,160,160)
  const float* w_vh0 = (const float*)d_in[2];
  const float* w_f0  = (const float*)d_in[3];
  const float* w_n0  = (const float*)d_in[4];
  const float* w_vh1 = (const float*)d_in[5];
  const float* w_f1  = (const float*)d_in[6];
  const float* w_n1  = (const float*)d_in[7];
  const float* w_vh2 = (const float*)d_in[8];
  const float* w_f2  = (const float*)d_in[9];
  const float* w_n2  = (const float*)d_in[10];
  const float* w_vh3 = (const float*)d_in[11];
  const float* w_f3  = (const float*)d_in[12];
  const float* w_n3  = (const float*)d_in[13];
  const float* b0    = (const float*)d_in[14];
  const float* g1    = (const float*)d_in[15];
  const float* be1   = (const float*)d_in[16];
  const float* g2    = (const float*)d_in[17];
  const float* be2   = (const float*)d_in[18];
  const float* g3    = (const float*)d_in[19];
  const float* be3   = (const float*)d_in[20];
  const float* w_vh4 = (const float*)d_in[21];
  const float* w_f4  = (const float*)d_in[22];
  const float* b4    = (const float*)d_in[23];
  float* outp = (float*)d_out;

  // workspace layout: 93,041,472 B total (identical to R2-R13)
  float* fws   = (float*)d_ws;
  float* seqT3 = fws;                             // 537,600 f (interleaved)
  u64*   sk    = (u64*)(seqT3 + 537600);          // 21*14*5184 u64
  float* X     = (float*)(sk + 1524096);          // 9,801,000 f
  float* A     = X + 9801000;                     // 9,801,000 f
  int*   fsi   = (int*)(A + 9801000);             // 72,576 int
  float* wsD   = X;                               // alias: 2625*5184 f spans X+A

  k0_transpose<<<dim3(160, 7), 160, 0, stream>>>(seq, seqT3);
  k_init<<<(1524096 + 255) / 256, 256, 0, stream>>>(sk, 1524096);
  for (int c = 0; c < NCHUNK; ++c) {
    k1_dist<<<CHUNK, 128, 0, stream>>>(seqT3, wsD, c * CHUNK);
    k2_topk<<<dim3(81, NSLOT), 256, 0, stream>>>(wsD, sk, c * CHUNK);
  }
  k_merge<<<81, 64, 0, stream>>>(sk, fsi);
  k3_layers<<<dim3(18, 15), 256, 0, stream>>>(seq, fsi, X);

  // L0: X -> A -> X -> A(1200) [+b0, relu]
  k4a_in<<<dim3(15, 750), 256, 0, stream>>>(X, w_vh0, A);
  k4a_bd<<<dim3(3, 750), 256, 0, stream>>>(X, w_vh0, A);
  k4b_f <<<dim3(9, 225), 256, 0, stream>>>(A, w_f0, X);
  k4c_n<15, 8><<<dim3(9, 150), 256, 0, stream>>>(X, w_n0, b0, A, 1);
  // L1
  k4a_in<<<dim3(15, 400), 256, 0, stream>>>(A, w_vh1, X);
  k4a_bd<<<dim3(3, 400), 256, 0, stream>>>(A, w_vh1, X);
  k4b_f <<<dim3(9, 120), 256, 0, stream>>>(X, w_f1, A);
  k4c_n<8, 4><<<dim3(9, 150), 256, 0, stream>>>(A, w_n1, nullptr, X, 0);
  k_bn<<<600, 256, 0, stream>>>(X, g1, be1);
  // L2
  k4a_in<<<dim3(15, 200), 256, 0, stream>>>(X, w_vh2, A);
  k4a_bd<<<dim3(3, 200), 256, 0, stream>>>(X, w_vh2, A);
  k4b_f <<<dim3(9, 60), 256, 0, stream>>>(A, w_f2, X);
  k4c_n<4, 2><<<dim3(9, 150), 256, 0, stream>>>(X, w_n2, nullptr, A, 0);
  k_bn<<<300, 256, 0, stream>>>(A, g2, be2);
  // L3
  k4a_in<<<dim3(15, 100), 256, 0, stream>>>(A, w_vh3, X);
  k4a_bd<<<dim3(3, 100), 256, 0, stream>>>(A, w_vh3, X);
  k4b_f <<<dim3(9, 30), 256, 0, stream>>>(X, w_f3, A);
  k4c_n<2, 1><<<dim3(9, 150), 256, 0, stream>>>(A, w_n3, nullptr, X, 0);
  k_bn<<<150, 256, 0, stream>>>(X, g3, be3);
  // L4
  k4a_in<<<dim3(15, 50), 256, 0, stream>>>(X, w_vh4, A);
  k4a_bd<<<dim3(3, 50), 256, 0, stream>>>(X, w_vh4, A);
  k_final<<<18, 256, 0, stream>>>(A, w_f4, b4, seq, outp);
}

// Round 15
// 1755.481 us; speedup vs baseline: 1.0410x; 1.0410x over previous
//
#include <hip/hip_runtime.h>
#include <cstdint>
#include <cstddef>

// ---------------- constants ----------------
#define H160   160
#define HD     86          // h-74
#define GW     72          // grid width (72x72 points)
#define PG     5184        // 72*72
#define P66    4356        // 66*66
#define NPAIR  2178        // P66/2
#define IDX146 21316       // 146*146
#define NVNH   5625        // 75*75
#define SELF_CAND 19687    // 3*5625 + 37*75 + 37
#define CHUNK  2625        // candidates per chunk (39375 = 15*2625)
#define NCHUNK 15
#define NSLOT  21
#define SLOTLEN 125
typedef unsigned long long u64;
struct F3 { float x, y, z; };

// ---------------- k0: transpose seq -> seqT3[t][x][y][c] (3-ch interleaved) ----
__global__ void k0_transpose(const float* __restrict__ seq, float* __restrict__ seqT3) {
  int t7 = blockIdx.y;           // frame 0..6
  int x  = blockIdx.x;           // col 0..159
  int y  = threadIdx.x;          // row 0..159
  int o = ((t7 * H160 + x) * H160 + y) * 3;
  seqT3[o + 0] = seq[(0 * 7 + t7) * 25600 + y * H160 + x];
  seqT3[o + 1] = seq[(1 * 7 + t7) * 25600 + y * H160 + x];
  seqT3[o + 2] = seq[(2 * 7 + t7) * 25600 + y * H160 + x];
}

// ---------------- init state keys to max ----------------
__global__ void k_init(u64* __restrict__ sk, int n) {
  int i = (int)blockIdx.x * 256 + threadIdx.x;
  if (i < n) sk[i] = ~0ULL;
}

// ---------------- k1: per-candidate boxed distance field (bitwise-replicates
// numpy sequential fp32 cumsum box15; Markstein div-by-3; phase-1 emits
// row-boxed values via static 16-ring; 25.1 KB LDS, 6 blocks/CU). ----
__global__ __launch_bounds__(128) void k1_dist(const float* __restrict__ seqT3,
                                               float* __restrict__ wsD, int chunkBase) {
  __shared__ float vb[HD][73];   // row-boxed values, padded stride 73
  const float R3 = 0.33333334f;  // RN(1/3)
  int cand = chunkBase + (int)blockIdx.x;
  int ts = cand / NVNH;
  int rr = cand % NVNH;
  int vs = rr / 75;
  int hv = rr % 75;
  int t = threadIdx.x;
  if (t < HD) {
    const F3* pa = (const F3*)seqT3 + ((ts * H160 + hv) * H160 + (vs + t));
    const F3* pb = (const F3*)seqT3 + ((3  * H160 + 37) * H160 + (37 + t));
    float c0 = 0.f;
    float ring[16];
#pragma unroll 1
    for (int blk = 0; blk < 5; ++blk) {          // u = 0..79 in 16-step frames
      int x0 = blk * 16;
#pragma unroll
      for (int half = 0; half < 2; ++half) {     // 8-load / 8-compute halves
        F3 Av[8], Bv[8];
#pragma unroll
        for (int k = 0; k < 8; ++k) {
          int u = x0 + half * 8 + k;
          Av[k] = pa[u * H160];
          Bv[k] = pb[u * H160];
        }
#pragma unroll
        for (int k = 0; k < 8; ++k) {
          int u  = x0 + half * 8 + k;
          int ki = half * 8 + k;                 // = u & 15 (static)
          float d0 = __fsub_rn(Av[k].x, Bv[k].x);
          float d1 = __fsub_rn(Av[k].y, Bv[k].y);
          float d2 = __fsub_rn(Av[k].z, Bv[k].z);
          float s  = __fadd_rn(__fadd_rn(__fmul_rn(d0, d0), __fmul_rn(d1, d1)), __fmul_rn(d2, d2));
          float q0 = __fmul_rn(s, R3);
          float e  = __builtin_fmaf(-3.0f, q0, s);
          float dd = __builtin_fmaf(e, R3, q0);
          c0 = __fadd_rn(c0, dd);
          ring[ki] = c0;
          if (u >= 14) {
            int j = u - 14;
            vb[t][j] = (j == 0) ? c0 : __fsub_rn(c0, ring[(ki + 1) & 15]); // c_{u-15}
          }
        }
      }
    }
    {                                            // tail u = 80..85 (ki = k, static)
      F3 Av[6], Bv[6];
#pragma unroll
      for (int k = 0; k < 6; ++k) {
        Av[k] = pa[(80 + k) * H160];
        Bv[k] = pb[(80 + k) * H160];
      }
#pragma unroll
      for (int k = 0; k < 6; ++k) {
        float d0 = __fsub_rn(Av[k].x, Bv[k].x);
        float d1 = __fsub_rn(Av[k].y, Bv[k].y);
        float d2 = __fsub_rn(Av[k].z, Bv[k].z);
        float s  = __fadd_rn(__fadd_rn(__fmul_rn(d0, d0), __fmul_rn(d1, d1)), __fmul_rn(d2, d2));
        float q0 = __fmul_rn(s, R3);
        float e  = __builtin_fmaf(-3.0f, q0, s);
        float dd = __builtin_fmaf(e, R3, q0);
        c0 = __fadd_rn(c0, dd);
        ring[k] = c0;                            // (80+k)&15 = k
        vb[t][66 + k] = __fsub_rn(c0, ring[(k + 1) & 15]); // c_{65+k}
      }
    }
  }
  __syncthreads();
  if (t < GW) {
    float cc = 0.f;
    float ring[16];
    float* D = wsD + (size_t)blockIdx.x * PG;
#pragma unroll
    for (int r = 0; r < HD; ++r) {
      float val = vb[r][t];
      cc = __fadd_rn(cc, val);
      ring[r & 15] = cc;
      if (r >= 14) {
        int gy = r - 14;
        float out = (gy == 0) ? cc : __fsub_rn(cc, ring[(r - 15) & 15]);
        D[gy * GW + t] = out;
      }
    }
  }
}

// ---------------- k2: banked top-14 via u64 sort keys (no state-threshold
// filter — that filter caused call-to-call divergence, permanently banned). ----
__global__ __launch_bounds__(256) void k2_topk(const float* __restrict__ wsD,
                                               u64* __restrict__ sk, int chunkBase) {
  __shared__ u64 lk[5][14][64];
  int tid = threadIdx.x;
  int w = tid >> 6, lane = tid & 63;
  int s = blockIdx.y;
  int pid = (int)blockIdx.x * 64 + lane;
  int st  = (w == 0) ? 96 : (w - 1) * 32;
  int cnt = (w == 0) ? 29 : 32;

  if (w == 0) {
#pragma unroll
    for (int k = 0; k < 14; ++k)
      lk[4][k][lane] = sk[(size_t)(s * 14 + k) * PG + pid];
  }
  float dv[32];
  const float* Dp = wsD + (size_t)(s * SLOTLEN + st) * PG + pid;
#pragma unroll
  for (int u = 0; u < 32; ++u)
    if (u < cnt) dv[u] = Dp[(size_t)u * PG];

  u64 key[14];
#pragma unroll
  for (int k = 0; k < 14; ++k) key[k] = ~0ULL;
  int cand0 = chunkBase + s * SLOTLEN + st;
#pragma unroll
  for (int u = 0; u < 32; ++u) {
    if (u < cnt) {
      int cand = cand0 + u;
      if (cand != SELF_CAND) {
        u64 nk = ((u64)__float_as_uint(dv[u]) << 32) | (unsigned)cand;
        if (nk < key[13]) {
#pragma unroll
          for (int j = 13; j >= 1; --j)
            key[j] = (nk < key[j - 1]) ? key[j - 1] : ((nk < key[j]) ? nk : key[j]);
          if (nk < key[0]) key[0] = nk;
        }
      }
    }
  }
#pragma unroll
  for (int k = 0; k < 14; ++k) lk[w][k][lane] = key[k];
  __syncthreads();
  if (w != 0) return;

  int h0 = 0, h1 = 0, h2 = 0, h3 = 0, h4 = 0;
  u64 a0 = lk[0][0][lane], a1 = lk[1][0][lane], a2 = lk[2][0][lane],
      a3 = lk[3][0][lane], a4 = lk[4][0][lane];
#pragma unroll
  for (int o = 0; o < 14; ++o) {
    u64 b01 = a0 < a1 ? a0 : a1; int j01 = a0 < a1 ? 0 : 1;
    u64 b23 = a2 < a3 ? a2 : a3; int j23 = a2 < a3 ? 2 : 3;
    u64 b03 = b01 < b23 ? b01 : b23; int j03 = b01 < b23 ? j01 : j23;
    u64 best = b03 < a4 ? b03 : a4; int bj = b03 < a4 ? j03 : 4;
    sk[(size_t)(s * 14 + o) * PG + pid] = best;
    h0 += (bj == 0); h1 += (bj == 1); h2 += (bj == 2); h3 += (bj == 3); h4 += (bj == 4);
    int c0 = h0 < 14 ? h0 : 13, c1 = h1 < 14 ? h1 : 13, c2 = h2 < 14 ? h2 : 13,
        c3 = h3 < 14 ? h3 : 13, c4 = h4 < 14 ? h4 : 13;
    a0 = lk[0][c0][lane]; if (h0 >= 14) a0 = ~0ULL;
    a1 = lk[1][c1][lane]; if (h1 >= 14) a1 = ~0ULL;
    a2 = lk[2][c2][lane]; if (h2 >= 14) a2 = ~0ULL;
    a3 = lk[3][c3][lane]; if (h3 >= 14) a3 = ~0ULL;
    a4 = lk[4][c4][lane]; if (h4 >= 14) a4 = ~0ULL;
  }
}

// ---------------- merge 21 slot lists -> final 14 indices ----------------
__global__ __launch_bounds__(64) void k_merge(const u64* __restrict__ sk,
                                              int* __restrict__ fsi) {
  int pid = (int)blockIdx.x * 64 + threadIdx.x;
  int gy = pid / GW, gx = pid % GW;
  int cur[NSLOT];
#pragma unroll
  for (int s = 0; s < NSLOT; ++s) cur[s] = 0;
  for (int o = 0; o < 14; ++o) {
    u64 bk = ~0ULL; int bs = 0;
#pragma unroll
    for (int s = 0; s < NSLOT; ++s) {
      int cc = cur[s] < 14 ? cur[s] : 13;
      u64 kk = sk[(size_t)(s * 14 + cc) * PG + pid];
      if (cur[s] >= 14) kk = ~0ULL;
      if (kk < bk) { bk = kk; bs = s; }
    }
#pragma unroll
    for (int s = 0; s < NSLOT; ++s) cur[s] += (bs == s) ? 1 : 0;
    int cand = (int)(unsigned)(bk & 0xffffffffULL);
    int ts = cand / NVNH;
    int rr = cand % NVNH;
    int vs = rr / 75, hv = rr % 75;
    fsi[o * PG + pid] = ts * IDX146 + (gy + vs) * 146 + (gx + hv);
  }
}

// ---------------- k3: build x_f = [layers(147), wts(3)] per neighbor slot ----------
__global__ void k3_layers(const float* __restrict__ seq, const int* __restrict__ fsi,
                          float* __restrict__ X) {
  int n = blockIdx.y;                       // 0..14
  int p = (int)blockIdx.x * 256 + threadIdx.x;
  if (p >= P66) return;
  int yo = p / 66, xo = p % 66;
  int y = yo + 6, x = xo + 6;
  float sv0 = seq[(0 * 7 + 3) * 25600 + (41 + y) * H160 + (41 + x)];
  float sv1 = seq[(1 * 7 + 3) * 25600 + (41 + y) * H160 + (41 + x)];
  float sv2 = seq[(2 * 7 + 3) * 25600 + (41 + y) * H160 + (41 + x)];
  float w0 = 0.f, w1 = 0.f, w2 = 0.f;
  for (int mv = 0; mv < 7; ++mv) {
    int dy = (y - mv) % 7; int gyy = y - dy;
    for (int mh = 0; mh < 7; ++mh) {
      int dx = (x - mh) % 7; int gxx = x - dx;
      int q = mv * 7 + mh;
      float v0, v1, v2;
      if (n == 0) { v0 = sv0; v1 = sv1; v2 = sv2; }
      else {
        int idx = fsi[(n - 1) * PG + gyy * GW + gxx];
        int fi = idx / IDX146; int rem = idx % IDX146;
        int pv = rem / 146, ph = rem % 146;
        int base = (4 + pv + dy) * H160 + (4 + ph + dx);
        v0 = seq[(0 * 7 + fi) * 25600 + base];
        v1 = seq[(1 * 7 + fi) * 25600 + base];
        v2 = seq[(2 * 7 + fi) * 25600 + base];
      }
      X[(size_t)(n * 150 + q * 3 + 0) * P66 + p] = v0;
      X[(size_t)(n * 150 + q * 3 + 1) * P66 + p] = v1;
      X[(size_t)(n * 150 + q * 3 + 2) * P66 + p] = v2;
      float e0 = v0 - sv0, e1 = v1 - sv1, e2 = v2 - sv2;
      w0 += e0 * e0; w1 += e1 * e1; w2 += e2 * e2;
    }
  }
  X[(size_t)(n * 150 + 147) * P66 + p] = w0 / 49.f;
  X[(size_t)(n * 150 + 148) * P66 + p] = w1 / 49.f;
  X[(size_t)(n * 150 + 149) * P66 + p] = w2 / 49.f;
}

// ---------------- k4a: reflect-pad 3 + grouped 7x7 conv (1 px/thread, hoisted
// reflect tables — best measured of 4 variants). FMA order (ic,ky,kx). ----
__global__ void k4a_vh(const float* __restrict__ in, const float* __restrict__ w,
                       float* __restrict__ out) {
  int g = blockIdx.y;                       // group, o0 = 3g
  int p = (int)blockIdx.x * 256 + threadIdx.x;
  if (p >= P66) return;
  int yo = p / 66, xo = p % 66;
  int o0 = g * 3;
  int iyt[7], ixt[7];
#pragma unroll
  for (int k = 0; k < 7; ++k) {
    int vy = yo + k - 3; iyt[k] = (vy < 0 ? -vy : (vy > 65 ? 130 - vy : vy)) * 66;
    int vx = xo + k - 3; ixt[k] = vx < 0 ? -vx : (vx > 65 ? 130 - vx : vx);
  }
  float a0 = 0.f, a1 = 0.f, a2 = 0.f;
#pragma unroll
  for (int ic = 0; ic < 3; ++ic) {
    const float* ip = in + (size_t)(o0 + ic) * P66;
    const float* wp = w + (size_t)o0 * 147 + ic * 49;
#pragma unroll
    for (int ky = 0; ky < 7; ++ky) {
      const float* row = ip + iyt[ky];
#pragma unroll
      for (int kx = 0; kx < 7; ++kx) {
        float v = row[ixt[kx]];
        int wi = ky * 7 + kx;
        a0 = fmaf(v, wp[wi],       a0);
        a1 = fmaf(v, wp[147 + wi], a1);
        a2 = fmaf(v, wp[294 + wi], a2);
      }
    }
  }
  out[(size_t)(o0 + 0) * P66 + p] = a0;
  out[(size_t)(o0 + 1) * P66 + p] = a1;
  out[(size_t)(o0 + 2) * P66 + p] = a2;
}

// ---------------- k4b: 1x1 conv, groups of 150, 10 outputs x 2 px (float2) ----
__global__ void k4b_f(const float* __restrict__ in, const float* __restrict__ w,
                      float* __restrict__ out) {
  int ob = blockIdx.y * 10;
  int q = (int)blockIdx.x * 256 + threadIdx.x;
  if (q >= NPAIR) return;
  int p = q * 2;
  int gb = (ob / 150) * 150;
  float2 acc[10];
#pragma unroll
  for (int j = 0; j < 10; ++j) { acc[j].x = 0.f; acc[j].y = 0.f; }
  const float* ip = in + (size_t)gb * P66 + p;
  const float* w0 = w + (size_t)ob * 150;
  for (int f = 0; f < 150; ++f) {
    float2 v = *(const float2*)&ip[(size_t)f * P66];    // P66 even, p even -> 8B aligned
#pragma unroll
    for (int j = 0; j < 10; ++j) {
      float wv = w0[j * 150 + f];
      acc[j].x = fmaf(v.x, wv, acc[j].x);
      acc[j].y = fmaf(v.y, wv, acc[j].y);
    }
  }
#pragma unroll
  for (int j = 0; j < 10; ++j)
    *(float2*)&out[(size_t)(ob + j) * P66 + p] = acc[j];
}

// ---------------- k4c: neighbor-mix 1x1, 2 px/thread (float2) ----------
template<int NI, int NO>
__global__ void k4c_n(const float* __restrict__ in, const float* __restrict__ w,
                      const float* __restrict__ bias, float* __restrict__ out, int withbias) {
  int f = blockIdx.y;                       // 0..149
  int q = (int)blockIdx.x * 256 + threadIdx.x;
  if (q >= NPAIR) return;
  int p = q * 2;
  float2 acc[NO];
#pragma unroll
  for (int j = 0; j < NO; ++j) { acc[j].x = 0.f; acc[j].y = 0.f; }
#pragma unroll
  for (int nn = 0; nn < NI; ++nn) {
    float2 v = *(const float2*)&in[(size_t)(nn * 150 + f) * P66 + p];
#pragma unroll
    for (int j = 0; j < NO; ++j) {
      float wv = w[(f * NO + j) * NI + nn];
      acc[j].x = fmaf(v.x, wv, acc[j].x);
      acc[j].y = fmaf(v.y, wv, acc[j].y);
    }
  }
#pragma unroll
  for (int j = 0; j < NO; ++j) {
    float2 r = acc[j];
    if (withbias) {
      float b = bias[j * 150 + f];
      r.x += b; r.x = r.x > 0.f ? r.x : 0.f;
      r.y += b; r.y = r.y > 0.f ? r.y : 0.f;
    }
    *(float2*)&out[(size_t)(j * 150 + f) * P66 + p] = r;
  }
}

// ---------------- BN (train-mode batch stats over 66x66) + relu, in place --------
__global__ void k_bn(float* __restrict__ x, const float* __restrict__ g,
                     const float* __restrict__ be) {
  int c = blockIdx.x;
  float* xp = x + (size_t)c * P66;
  __shared__ float red[256];
  int t = threadIdx.x;
  float s = 0.f;
  for (int p = t; p < P66; p += 256) s += xp[p];
  red[t] = s; __syncthreads();
  for (int off = 128; off > 0; off >>= 1) { if (t < off) red[t] += red[t + off]; __syncthreads(); }
  float m = red[0] / (float)P66;
  __syncthreads();
  float s2 = 0.f;
  for (int p = t; p < P66; p += 256) { float dd = xp[p] - m; s2 += dd * dd; }
  red[t] = s2; __syncthreads();
  for (int off = 128; off > 0; off >>= 1) { if (t < off) red[t] += red[t + off]; __syncthreads(); }
  float var = red[0] / (float)P66;
  float sc = g[c] / sqrtf(var + 1e-5f);
  float sh = be[c] - m * sc;
  for (int p = t; p < P66; p += 256) { float r = fmaf(xp[p], sc, sh); xp[p] = r > 0.f ? r : 0.f; }
}

// ---------------- final: w_f4 (150->3) + b4, out = valid - y ----------------------
__global__ void k_final(const float* __restrict__ in, const float* __restrict__ wf,
                        const float* __restrict__ b4, const float* __restrict__ seq,
                        float* __restrict__ out) {
  int p = (int)blockIdx.x * 256 + threadIdx.x;
  if (p >= P66) return;
  int yo = p / 66, xo = p % 66;
  float a0 = 0.f, a1 = 0.f, a2 = 0.f;
  for (int f = 0; f < 150; ++f) {
    float v = in[(size_t)f * P66 + p];
    a0 = fmaf(v, wf[f],       a0);
    a1 = fmaf(v, wf[150 + f], a1);
    a2 = fmaf(v, wf[300 + f], a2);
  }
  float y0 = a0 + b4[0], y1 = a1 + b4[1], y2 = a2 + b4[2];
  int vo = (47 + yo) * H160 + (47 + xo);
  out[0 * P66 + p] = seq[(0 * 7 + 3) * 25600 + vo] - y0;
  out[1 * P66 + p] = seq[(1 * 7 + 3) * 25600 + vo] - y1;
  out[2 * P66 + p] = seq[(2 * 7 + 3) * 25600 + vo] - y2;
}

extern "C" void kernel_launch(void* const* d_in, const int* in_sizes, int n_in,
                              void* d_out, int out_size, void* d_ws, size_t ws_size,
                              hipStream_t stream) {
  const float* seq   = (const float*)d_in[0];   // (1,3,7,160,160)
  const float* w_vh0 = (const float*)d_in[2];
  const float* w_f0  = (const float*)d_in[3];
  const float* w_n0  = (const float*)d_in[4];
  const float* w_vh1 = (const float*)d_in[5];
  const float* w_f1  = (const float*)d_in[6];
  const float* w_n1  = (const float*)d_in[7];
  const float* w_vh2 = (const float*)d_in[8];
  const float* w_f2  = (const float*)d_in[9];
  const float* w_n2  = (const float*)d_in[10];
  const float* w_vh3 = (const float*)d_in[11];
  const float* w_f3  = (const float*)d_in[12];
  const float* w_n3  = (const float*)d_in[13];
  const float* b0    = (const float*)d_in[14];
  const float* g1    = (const float*)d_in[15];
  const float* be1   = (const float*)d_in[16];
  const float* g2    = (const float*)d_in[17];
  const float* be2   = (const float*)d_in[18];
  const float* g3    = (const float*)d_in[19];
  const float* be3   = (const float*)d_in[20];
  const float* w_vh4 = (const float*)d_in[21];
  const float* w_f4  = (const float*)d_in[22];
  const float* b4    = (const float*)d_in[23];
  float* outp = (float*)d_out;

  // workspace layout: 93,041,472 B total
  float* fws   = (float*)d_ws;
  float* seqT3 = fws;                             // 537,600 f (interleaved)
  u64*   sk    = (u64*)(seqT3 + 537600);          // 21*14*5184 u64
  float* X     = (float*)(sk + 1524096);          // 9,801,000 f
  float* A     = X + 9801000;                     // 9,801,000 f
  int*   fsi   = (int*)(A + 9801000);             // 72,576 int
  float* wsD   = X;                               // alias: 2625*5184 f spans X+A

  k0_transpose<<<dim3(160, 7), 160, 0, stream>>>(seq, seqT3);
  k_init<<<(1524096 + 255) / 256, 256, 0, stream>>>(sk, 1524096);
  for (int c = 0; c < NCHUNK; ++c) {
    k1_dist<<<CHUNK, 128, 0, stream>>>(seqT3, wsD, c * CHUNK);
    k2_topk<<<dim3(81, NSLOT), 256, 0, stream>>>(wsD, sk, c * CHUNK);
  }
  k_merge<<<81, 64, 0, stream>>>(sk, fsi);
  k3_layers<<<dim3(18, 15), 256, 0, stream>>>(seq, fsi, X);

  // L0: X -> A -> X -> A(1200) [+b0, relu]
  k4a_vh<<<dim3(18, 750), 256, 0, stream>>>(X, w_vh0, A);
  k4b_f <<<dim3(9, 225), 256, 0, stream>>>(A, w_f0, X);
  k4c_n<15, 8><<<dim3(9, 150), 256, 0, stream>>>(X, w_n0, b0, A, 1);
  // L1
  k4a_vh<<<dim3(18, 400), 256, 0, stream>>>(A, w_vh1, X);
  k4b_f <<<dim3(9, 120), 256, 0, stream>>>(X, w_f1, A);
  k4c_n<8, 4><<<dim3(9, 150), 256, 0, stream>>>(A, w_n1, nullptr, X, 0);
  k_bn<<<600, 256, 0, stream>>>(X, g1, be1);
  // L2
  k4a_vh<<<dim3(18, 200), 256, 0, stream>>>(X, w_vh2, A);
  k4b_f <<<dim3(9, 60), 256, 0, stream>>>(A, w_f2, X);
  k4c_n<4, 2><<<dim3(9, 150), 256, 0, stream>>>(X, w_n2, nullptr, A, 0);
  k_bn<<<300, 256, 0, stream>>>(A, g2, be2);
  // L3
  k4a_vh<<<dim3(18, 100), 256, 0, stream>>>(A, w_vh3, X);
  k4b_f <<<dim3(9, 30), 256, 0, stream>>>(X, w_f3, A);
  k4c_n<2, 1><<<dim3(9, 150), 256, 0, stream>>>(A, w_n3, nullptr, X, 0);
  k_bn<<<150, 256, 0, stream>>>(X, g3, be3);
  // L4
  k4a_vh<<<dim3(18, 50), 256, 0, stream>>>(X, w_vh4, A);
  k_final<<<18, 256, 0, stream>>>(A, w_f4, b4, seq, outp);
}